// Round 3
// baseline (6103.703 us; speedup 1.0000x reference)
//
#include <hip/hip_runtime.h>

// LSTM T=128,B=64,I=H=1024,L=8 — diagonal schedule, A-fragment-layout activations.
// R3: no LDS staging / no mid-loop barriers. x and h live in global memory
// pre-permuted into the MFMA A-operand lane order, so the K-loop is a pure
// streaming (load,mfma) pipeline. 16-wide unit strips -> 512 WGs/diag = 2 WG/CU.
//
// ws layout: packedW bf16 [L][256 ntile][64 kc][64 lane][8]      134,217,728 B
//            xA     bf16 [T][32 kc][4 mt][64 lane][8]            16,777,216 B
//            bias   f32  [L][4096]                                   131,072 B
//            c_state f32 [L][B][H]                                 2,097,152 B
//            hA     bf16 [2 parity][L][32 kc][4 mt][64 lane][8]   2,097,152 B

typedef __attribute__((ext_vector_type(8))) short short8;
typedef __attribute__((ext_vector_type(4))) float f32x4;

#define T_ 128
#define B_ 64
#define H_ 1024
#define L_ 8
#define SLAB 65536   // shorts per [B,H] A-frag slab (32*4*64*8)

__device__ __forceinline__ unsigned short f2bf(float f) {
    unsigned u = __builtin_bit_cast(unsigned, f);
    u += 0x7fff + ((u >> 16) & 1);          // round-to-nearest-even
    return (unsigned short)(u >> 16);
}

// Pack Wih|Whh (fp32 [L,4,1024,1024] each) into bf16 B-fragment lane order:
// packed[((l*256+ntile)*64+kc)*512 + lane*8 + j] = W[k][n], n=ntile*16+(lane&15),
// k = kc*32 + (lane>>4)*8 + j  (k<1024 -> Wih, else Whh).
__global__ void pack_weights(const float* __restrict__ Wih, const float* __restrict__ Whh,
                             unsigned short* __restrict__ packedW) {
    int tid = blockIdx.x * 256 + threadIdx.x;          // 8,388,608 threads
    int lane = tid & 63;
    int kchunk = (tid >> 6) & 63;
    int ntile = (tid >> 12) & 255;
    int l = tid >> 20;
    int n = ntile * 16 + (lane & 15);
    int g = n >> 10;
    int h = n & 1023;
    int kbase = kchunk * 32 + ((lane >> 4) << 3);
    short8 v;
#pragma unroll
    for (int j = 0; j < 8; ++j) {
        int k = kbase + j;
        float w = (k < 1024) ? Wih[(((l * 4 + g) * 1024 + k) << 10) + h]
                             : Whh[(((l * 4 + g) * 1024 + (k - 1024)) << 10) + h];
        v[j] = (short)f2bf(w);
    }
    *(short8*)(packedW + (size_t)tid * 8) = v;
}

// xA pack + bias + zero c_state/hA. 1,048,576 threads.
__global__ void prep_misc(const float* __restrict__ x, const float* __restrict__ bih,
                          const float* __restrict__ bhh, unsigned short* __restrict__ xA,
                          float* __restrict__ bias, float* __restrict__ c_state,
                          unsigned short* __restrict__ hA) {
    int tid = blockIdx.x * 256 + threadIdx.x;
    // task = (t, b, ioct): read x[t][b][ioct*8 .. +7] coalesced, write one short8
    int ioct = tid & 127;
    int b = (tid >> 7) & 63;
    int t = tid >> 13;
    int i0 = ioct * 8;
    const float* src = x + ((size_t)(t * 64 + b) << 10) + i0;
    short8 v;
#pragma unroll
    for (int j = 0; j < 8; ++j) v[j] = (short)f2bf(src[j]);
    int kc = i0 >> 5;
    int q = (i0 >> 3) & 3;
    int mt = b >> 4;
    int m = b & 15;
    *(short8*)(xA + (size_t)t * SLAB + (((kc * 4 + mt) * 64 + q * 16 + m) << 3)) = v;

    if (tid < L_ * 4096) bias[tid] = bih[tid] + bhh[tid];
    if (tid < L_ * B_ * H_ / 2) { c_state[2 * tid] = 0.f; c_state[2 * tid + 1] = 0.f; }
    if (tid < 131072) *(short8*)(hA + (size_t)tid * 8) = (short8)0;
}

// One diagonal d: stage l = lmin + blockIdx.y (t = d - l).
// blockIdx.x in [0,64): 16-wide hidden-unit strip. wave = gate.
__global__ __launch_bounds__(256)
void lstm_diag(const unsigned short* __restrict__ packedW,
               const unsigned short* __restrict__ xA,
               const float* __restrict__ bias,
               float* __restrict__ c_state,
               unsigned short* __restrict__ hA,
               float* __restrict__ out,
               int d, int lmin) {
    __shared__ float Gbuf[4 * 64 * 17];     // 17408 B
    const int l = lmin + blockIdx.y;
    const int t = d - l;
    const int strip = blockIdx.x;           // 16-unit strip
    const int tid = threadIdx.x;
    const int lane = tid & 63;
    const int g = tid >> 6;                 // wave index == gate (i,f,c,o)
    const int m = lane & 15;
    const int q = lane >> 4;

    const unsigned short* A0 = (l == 0) ? (xA + (size_t)t * SLAB)
                                        : (hA + (size_t)((t & 1) * L_ + (l - 1)) * SLAB);
    const unsigned short* A1 = hA + (size_t)(((t + 1) & 1) * L_ + l) * SLAB;
    const unsigned short* Bp = packedW
        + ((size_t)l * 256 + g * 64 + strip) * 32768 + lane * 8;

    f32x4 acc[4];
#pragma unroll
    for (int mt = 0; mt < 4; ++mt) acc[mt] = (f32x4)0.f;

#pragma unroll 8
    for (int kc = 0; kc < 32; ++kc) {
        short8 bfr = *(const short8*)(Bp + kc * 512);
        short8 a[4];
#pragma unroll
        for (int mt = 0; mt < 4; ++mt)
            a[mt] = *(const short8*)(A0 + (((kc * 4 + mt) * 64 + lane) << 3));
#pragma unroll
        for (int mt = 0; mt < 4; ++mt)
            acc[mt] = __builtin_amdgcn_mfma_f32_16x16x32_bf16(a[mt], bfr, acc[mt], 0, 0, 0);
    }
#pragma unroll 8
    for (int kc = 0; kc < 32; ++kc) {
        short8 bfr = *(const short8*)(Bp + (kc + 32) * 512);
        short8 a[4];
#pragma unroll
        for (int mt = 0; mt < 4; ++mt)
            a[mt] = *(const short8*)(A1 + (((kc * 4 + mt) * 64 + lane) << 3));
#pragma unroll
        for (int mt = 0; mt < 4; ++mt)
            acc[mt] = __builtin_amdgcn_mfma_f32_16x16x32_bf16(a[mt], bfr, acc[mt], 0, 0, 0);
    }

    // C/D layout: row(b) = q*4+r, col(u) = m
#pragma unroll
    for (int mt = 0; mt < 4; ++mt)
#pragma unroll
        for (int r = 0; r < 4; ++r)
            Gbuf[(g * 64 + mt * 16 + q * 4 + r) * 17 + m] = acc[mt][r];
    __syncthreads();

    if (tid < 128) {
        int b = tid >> 1;
        int oct = tid & 1;                  // which 8-unit half of the strip
        int uH0 = strip * 16 + oct * 8;     // global hidden-unit base (mult of 8)
        const float* bs = bias + l * 4096;
        float* cp = c_state + ((l * 64 + b) << 10) + uH0;
        int kcH = uH0 >> 5, qH = (uH0 >> 3) & 3;
        unsigned short* hp = hA + (size_t)((t & 1) * L_ + l) * SLAB
                           + (((kcH * 4 + (b >> 4)) * 64 + qH * 16 + (b & 15)) << 3);
        short8 hv;
#pragma unroll
        for (int j = 0; j < 8; ++j) {
            int ul = oct * 8 + j;
            float gi = Gbuf[(0 * 64 + b) * 17 + ul] + bs[uH0 + j];
            float gf = Gbuf[(1 * 64 + b) * 17 + ul] + bs[1024 + uH0 + j];
            float gc = Gbuf[(2 * 64 + b) * 17 + ul] + bs[2048 + uH0 + j];
            float go = Gbuf[(3 * 64 + b) * 17 + ul] + bs[3072 + uH0 + j];
            float ig = 1.f / (1.f + __expf(-gi));
            float fg = 1.f / (1.f + __expf(-gf));
            float cg = tanhf(gc);
            float og = 1.f / (1.f + __expf(-go));
            float cnew = fg * cp[j] + ig * cg;
            cp[j] = cnew;
            float hnew = og * tanhf(cnew);
            hv[j] = (short)f2bf(hnew);
            if (l == 7 && t == 127) out[(b << 10) + uH0 + j] = hnew;
        }
        *(short8*)hp = hv;
    }
}

extern "C" void kernel_launch(void* const* d_in, const int* in_sizes, int n_in,
                              void* d_out, int out_size, void* d_ws, size_t ws_size,
                              hipStream_t stream) {
    const float* x   = (const float*)d_in[0];
    const float* Wih = (const float*)d_in[1];
    const float* Whh = (const float*)d_in[2];
    const float* bih = (const float*)d_in[3];
    const float* bhh = (const float*)d_in[4];
    float* out = (float*)d_out;

    char* ws = (char*)d_ws;
    unsigned short* packedW = (unsigned short*)ws;
    unsigned short* xA      = (unsigned short*)(ws + 134217728);
    float* bias             = (float*)(ws + 134217728 + 16777216);
    float* c_state          = (float*)(ws + 134217728 + 16777216 + 131072);
    unsigned short* hA      = (unsigned short*)(ws + 134217728 + 16777216 + 131072 + 2097152);

    hipLaunchKernelGGL(pack_weights, dim3(32768), dim3(256), 0, stream, Wih, Whh, packedW);
    hipLaunchKernelGGL(prep_misc, dim3(4096), dim3(256), 0, stream,
                       x, bih, bhh, xA, bias, c_state, hA);
    for (int d = 0; d <= 134; ++d) {
        int lmin = d > 127 ? d - 127 : 0;
        int lmax = d < 7 ? d : 7;
        hipLaunchKernelGGL(lstm_diag, dim3(64, lmax - lmin + 1), dim3(256), 0, stream,
                           packedW, xA, bias, c_state, hA, out, d, lmin);
    }
}

// Round 4
// 4014.850 us; speedup vs baseline: 1.5203x; 1.5203x over previous
//
#include <hip/hip_runtime.h>

// LSTM T=128,B=64,I=H=1024,L=8 — diagonal schedule, A-frag-layout activations.
// R4: split-K waves. Each wave computes ALL 4 gates for a 16-unit strip over a
// K-quarter (512 of 2048) -> each A fragment loaded once feeds 4 MFMAs (4x less
// A traffic than R3). No mid-loop barriers; one LDS split-K reduction at end.
//
// ws layout: packedW bf16 [L][256 ntile][64 kc][64 lane][8]      134,217,728 B
//            xA     bf16 [T][32 kc][4 mt][64 lane][8]            16,777,216 B
//            bias   f32  [L][4096]                                   131,072 B
//            c_state f32 [L][B][H]                                 2,097,152 B
//            hA     bf16 [2 parity][L][32 kc][4 mt][64 lane][8]   2,097,152 B

typedef __attribute__((ext_vector_type(8))) short short8;
typedef __attribute__((ext_vector_type(4))) float f32x4;

#define T_ 128
#define B_ 64
#define H_ 1024
#define L_ 8
#define SLAB 65536   // shorts per [B,H] A-frag slab (32*4*64*8)

__device__ __forceinline__ unsigned short f2bf(float f) {
    unsigned u = __builtin_bit_cast(unsigned, f);
    u += 0x7fff + ((u >> 16) & 1);          // round-to-nearest-even
    return (unsigned short)(u >> 16);
}

// Pack Wih|Whh (fp32 [L,4,1024,1024] each) into bf16 B-fragment lane order:
// packed[((l*256+ntile)*64+kc)*512 + lane*8 + j] = W[k][n], n=ntile*16+(lane&15),
// k = kc*32 + (lane>>4)*8 + j  (k<1024 -> Wih, else Whh).
__global__ void pack_weights(const float* __restrict__ Wih, const float* __restrict__ Whh,
                             unsigned short* __restrict__ packedW) {
    int tid = blockIdx.x * 256 + threadIdx.x;          // 8,388,608 threads
    int lane = tid & 63;
    int kchunk = (tid >> 6) & 63;
    int ntile = (tid >> 12) & 255;
    int l = tid >> 20;
    int n = ntile * 16 + (lane & 15);
    int g = n >> 10;
    int h = n & 1023;
    int kbase = kchunk * 32 + ((lane >> 4) << 3);
    short8 v;
#pragma unroll
    for (int j = 0; j < 8; ++j) {
        int k = kbase + j;
        float w = (k < 1024) ? Wih[(((l * 4 + g) * 1024 + k) << 10) + h]
                             : Whh[(((l * 4 + g) * 1024 + (k - 1024)) << 10) + h];
        v[j] = (short)f2bf(w);
    }
    *(short8*)(packedW + (size_t)tid * 8) = v;
}

// xA pack + bias + zero c_state/hA. 1,048,576 threads.
__global__ void prep_misc(const float* __restrict__ x, const float* __restrict__ bih,
                          const float* __restrict__ bhh, unsigned short* __restrict__ xA,
                          float* __restrict__ bias, float* __restrict__ c_state,
                          unsigned short* __restrict__ hA) {
    int tid = blockIdx.x * 256 + threadIdx.x;
    int ioct = tid & 127;
    int b = (tid >> 7) & 63;
    int t = tid >> 13;
    int i0 = ioct * 8;
    const float* src = x + ((size_t)(t * 64 + b) << 10) + i0;
    short8 v;
#pragma unroll
    for (int j = 0; j < 8; ++j) v[j] = (short)f2bf(src[j]);
    int kc = i0 >> 5;
    int q = (i0 >> 3) & 3;
    int mt = b >> 4;
    int m = b & 15;
    *(short8*)(xA + (size_t)t * SLAB + (((kc * 4 + mt) * 64 + q * 16 + m) << 3)) = v;

    if (tid < L_ * 4096) bias[tid] = bih[tid] + bhh[tid];
    if (tid < L_ * B_ * H_ / 2) { c_state[2 * tid] = 0.f; c_state[2 * tid + 1] = 0.f; }
    if (tid < 131072) *(short8*)(hA + (size_t)tid * 8) = (short8)0;
}

// One diagonal d: stage l = lmin + blockIdx.y (t = d - l).
// blockIdx.x in [0,64): 16-unit strip. wave = K-quarter; each wave does all 4 gates.
__global__ __launch_bounds__(256, 2)
void lstm_diag(const unsigned short* __restrict__ packedW,
               const unsigned short* __restrict__ xA,
               const float* __restrict__ bias,
               float* __restrict__ c_state,
               unsigned short* __restrict__ hA,
               float* __restrict__ out,
               int d, int lmin) {
    __shared__ float P[4 * 4 * 16 * 68];    // [w][g][u][b pad68] = 69,632 B (2 WG/CU)
    const int l = lmin + blockIdx.y;
    const int t = d - l;
    const int strip = blockIdx.x;
    const int tid = threadIdx.x;
    const int lane = tid & 63;
    const int kq = tid >> 6;                // split-K quarter
    const int m = lane & 15;
    const int q = lane >> 4;

    const unsigned short* slab0 = (l == 0) ? (xA + (size_t)t * SLAB)
                                           : (hA + (size_t)((t & 1) * L_ + (l - 1)) * SLAB);
    const unsigned short* slab1 = hA + (size_t)(((t + 1) & 1) * L_ + l) * SLAB;
    const unsigned short* A = (kq < 2) ? slab0 : slab1;
    const int kc0 = (kq & 1) * 16;          // chunk base within slab (16 chunks = K/2=512)

    const unsigned short* Bp0 = packedW + (((size_t)l * 256 + 0 * 64 + strip) * 32768)
                              + (size_t)(kq * 16) * 512 + lane * 8;
    const unsigned short* Bp1 = Bp0 + (size_t)64 * 32768;
    const unsigned short* Bp2 = Bp0 + (size_t)128 * 32768;
    const unsigned short* Bp3 = Bp0 + (size_t)192 * 32768;

    f32x4 acc[4][4];                        // [gate][mt]
#pragma unroll
    for (int g = 0; g < 4; ++g)
#pragma unroll
        for (int mt = 0; mt < 4; ++mt) acc[g][mt] = (f32x4)0.f;

#pragma unroll 2
    for (int kc = 0; kc < 16; ++kc) {
        short8 a[4];
#pragma unroll
        for (int mt = 0; mt < 4; ++mt)
            a[mt] = *(const short8*)(A + (((kc0 + kc) * 4 + mt) * 64 + lane) * 8);
        short8 b0 = *(const short8*)(Bp0 + kc * 512);
        short8 b1 = *(const short8*)(Bp1 + kc * 512);
        short8 b2 = *(const short8*)(Bp2 + kc * 512);
        short8 b3 = *(const short8*)(Bp3 + kc * 512);
#pragma unroll
        for (int mt = 0; mt < 4; ++mt) {
            acc[0][mt] = __builtin_amdgcn_mfma_f32_16x16x32_bf16(a[mt], b0, acc[0][mt], 0, 0, 0);
            acc[1][mt] = __builtin_amdgcn_mfma_f32_16x16x32_bf16(a[mt], b1, acc[1][mt], 0, 0, 0);
            acc[2][mt] = __builtin_amdgcn_mfma_f32_16x16x32_bf16(a[mt], b2, acc[2][mt], 0, 0, 0);
            acc[3][mt] = __builtin_amdgcn_mfma_f32_16x16x32_bf16(a[mt], b3, acc[3][mt], 0, 0, 0);
        }
    }

    // write split-K partials: P[kq][g][u=m][b = mt*16+q*4+r]  (b128, conflict-free)
#pragma unroll
    for (int g = 0; g < 4; ++g)
#pragma unroll
        for (int mt = 0; mt < 4; ++mt)
            *(f32x4*)&P[((kq * 4 + g) * 16 + m) * 68 + mt * 16 + q * 4] = acc[g][mt];
    __syncthreads();

    // epilogue: thread = (u, b-quad); reduce 4 K-partials, activations, c/h update
    {
        const int u = tid & 15;
        const int b0i = (tid >> 4) << 2;
        const int ug = strip * 16 + u;
        f32x4 G[4];
#pragma unroll
        for (int g = 0; g < 4; ++g) G[g] = (f32x4)0.f;
#pragma unroll
        for (int w = 0; w < 4; ++w)
#pragma unroll
            for (int g = 0; g < 4; ++g)
                G[g] += *(const f32x4*)&P[((w * 4 + g) * 16 + u) * 68 + b0i];
        const float* bs = bias + l * 4096;
        const float bi = bs[ug], bff = bs[1024 + ug], bc = bs[2048 + ug], bo = bs[3072 + ug];
        unsigned short* hslab = hA + (size_t)((t & 1) * L_ + l) * SLAB;
        const int hbase = ((ug >> 5) * 4) * 64 * 8 + (((ug >> 3) & 3) * 16) * 8 + (ug & 7);
#pragma unroll
        for (int rb = 0; rb < 4; ++rb) {
            int b = b0i + rb;
            float gi = G[0][rb] + bi;
            float gf = G[1][rb] + bff;
            float gc = G[2][rb] + bc;
            float go = G[3][rb] + bo;
            float ig = 1.f / (1.f + __expf(-gi));
            float fg = 1.f / (1.f + __expf(-gf));
            float cg = tanhf(gc);
            float og = 1.f / (1.f + __expf(-go));
            int cidx = ((l * 64 + b) << 10) + ug;
            float cnew = fg * c_state[cidx] + ig * cg;
            c_state[cidx] = cnew;
            float hnew = og * tanhf(cnew);
            hslab[hbase + ((b >> 4) * 64 + (b & 15)) * 8] = f2bf(hnew);
            if (l == 7 && t == 127) out[(b << 10) + ug] = hnew;
        }
    }
}

extern "C" void kernel_launch(void* const* d_in, const int* in_sizes, int n_in,
                              void* d_out, int out_size, void* d_ws, size_t ws_size,
                              hipStream_t stream) {
    const float* x   = (const float*)d_in[0];
    const float* Wih = (const float*)d_in[1];
    const float* Whh = (const float*)d_in[2];
    const float* bih = (const float*)d_in[3];
    const float* bhh = (const float*)d_in[4];
    float* out = (float*)d_out;

    char* ws = (char*)d_ws;
    unsigned short* packedW = (unsigned short*)ws;
    unsigned short* xA      = (unsigned short*)(ws + 134217728);
    float* bias             = (float*)(ws + 134217728 + 16777216);
    float* c_state          = (float*)(ws + 134217728 + 16777216 + 131072);
    unsigned short* hA      = (unsigned short*)(ws + 134217728 + 16777216 + 131072 + 2097152);

    hipLaunchKernelGGL(pack_weights, dim3(32768), dim3(256), 0, stream, Wih, Whh, packedW);
    hipLaunchKernelGGL(prep_misc, dim3(4096), dim3(256), 0, stream,
                       x, bih, bhh, xA, bias, c_state, hA);
    for (int d = 0; d <= 134; ++d) {
        int lmin = d > 127 ? d - 127 : 0;
        int lmax = d < 7 ? d : 7;
        hipLaunchKernelGGL(lstm_diag, dim3(64, lmax - lmin + 1), dim3(256), 0, stream,
                           packedW, xA, bias, c_state, hA, out, d, lmin);
    }
}